// Round 4
// baseline (184.165 us; speedup 1.0000x reference)
//
#include <hip/hip_runtime.h>
#include <stdint.h>

typedef unsigned short u16;
typedef __attribute__((ext_vector_type(8))) short bf16x8;
typedef __attribute__((ext_vector_type(4))) float f32x4;

__device__ __forceinline__ u16 f2bf(float f) {
    union { float f; uint32_t u; } v; v.f = f;
    uint32_t u = v.u + 0x7fffu + ((v.u >> 16) & 1u);
    return (u16)(u >> 16);
}
// fast positive-value pack: round-half-up (bias only on exact ties)
__device__ __forceinline__ uint32_t packbf(float a, float b) {
    union { float f; uint32_t u; } ua, ub; ua.f = a; ub.f = b;
    return ((ua.u + 0x8000u) >> 16) | ((ub.u + 0x8000u) & 0xffff0000u);
}

__device__ __forceinline__ void gld16(const void* g, void* l) {
    __builtin_amdgcn_global_load_lds((const __attribute__((address_space(1))) void*)g,
                                     (__attribute__((address_space(3))) void*)l,
                                     16, 0, 0);
}

// in-place cross-lane swap: a.row1<->b.row0, a.row3<->b.row2 (rows = 16-lane groups)
__device__ __forceinline__ void plswap16(uint32_t& a, uint32_t& b) {
    asm volatile("v_permlane16_swap_b32 %0, %1" : "+v"(a), "+v"(b));
}

// ---------------- pack kernels ----------------

__global__ void cvt_bf16_kernel(const float* __restrict__ s, u16* __restrict__ d, int n4) {
    int i = blockIdx.x * blockDim.x + threadIdx.x;
    const int stride = gridDim.x * blockDim.x;
    for (; i < n4; i += stride) {
        float4 v = ((const float4*)s)[i];
        ushort4 o;
        o.x = f2bf(v.x); o.y = f2bf(v.y); o.z = f2bf(v.z); o.w = f2bf(v.w);
        ((ushort4*)d)[i] = o;
    }
}

// dst[d][k] = src[k][d], both 1024x1024
__global__ void transpose_bf16_kernel(const float* __restrict__ src, u16* __restrict__ dst) {
    __shared__ float tile[32][33];
    const int tx = threadIdx.x, ty = threadIdx.y;
    const int bx = blockIdx.x * 32, by = blockIdx.y * 32;
#pragma unroll
    for (int i = ty; i < 32; i += 8)
        tile[i][tx] = src[(size_t)(by + i) * 1024 + bx + tx];
    __syncthreads();
#pragma unroll
    for (int i = ty; i < 32; i += 8)
        dst[(size_t)(bx + i) * 1024 + by + tx] = f2bf(tile[tx][i]);
}

// ---------------- GEMM (128x128 tile, BK=32, 4 waves) ----------------

template <int EPI>
__global__ __launch_bounds__(256) void gemm128(
    const u16* __restrict__ A, const u16* __restrict__ Bt,
    const float* __restrict__ bias0, const float* __restrict__ bias1,
    const float* __restrict__ bias2,
    u16* __restrict__ o_q, u16* __restrict__ o_k, u16* __restrict__ o_vt,
    float* __restrict__ o_f)
{
    constexpr int K = 1024;
    __shared__ u16 As[128 * 32];
    __shared__ u16 Bs[128 * 32];
    const int t = threadIdx.x;
    const int lane = t & 63, w = t >> 6;
    const int wm = w >> 1, wn = w & 1;
    const int g = lane >> 4, r = lane & 15;
    const int mbase = blockIdx.y * 128, nbase = blockIdx.x * 128;

    const f32x4 zero4 = {0.f, 0.f, 0.f, 0.f};
    f32x4 acc[4][4];
#pragma unroll
    for (int m = 0; m < 4; ++m)
#pragma unroll
        for (int n = 0; n < 4; ++n) acc[m][n] = zero4;

    for (int k0 = 0; k0 < K; k0 += 32) {
#pragma unroll
        for (int i = 0; i < 2; ++i) {
            const int base = i * 256 + (w << 6);
            const int idx = base + lane;
            const int row = idx >> 2, cc = (idx & 3) << 3;
            gld16(A + (size_t)(mbase + row) * K + k0 + cc, (char*)As + base * 16);
            gld16(Bt + (size_t)(nbase + row) * K + k0 + cc, (char*)Bs + base * 16);
        }
        __syncthreads();

        bf16x8 af[4], bfr[4];
#pragma unroll
        for (int m = 0; m < 4; ++m)
            af[m] = *(const bf16x8*)&As[(wm * 64 + m * 16 + r) * 32 + g * 8];
#pragma unroll
        for (int n = 0; n < 4; ++n)
            bfr[n] = *(const bf16x8*)&Bs[(wn * 64 + n * 16 + r) * 32 + g * 8];
        __builtin_amdgcn_s_setprio(1);
#pragma unroll
        for (int m = 0; m < 4; ++m)
#pragma unroll
            for (int n = 0; n < 4; ++n)
                acc[m][n] = __builtin_amdgcn_mfma_f32_16x16x32_bf16(af[m], bfr[n], acc[m][n], 0, 0, 0);
        __builtin_amdgcn_s_setprio(0);
        __syncthreads();
    }

#pragma unroll
    for (int m = 0; m < 4; ++m) {
#pragma unroll
        for (int n = 0; n < 4; ++n) {
            const int c = nbase + wn * 64 + n * 16 + r;
#pragma unroll
            for (int j = 0; j < 4; ++j) {
                const int rr = mbase + wm * 64 + m * 16 + g * 4 + j;
                const float y = acc[m][n][j];
                if (EPI == 0) {
                    const int which = c >> 10, d = c & 1023;
                    const int b = rr >> 11, l = rr & 2047;
                    const int h = d >> 6, dd = d & 63;
                    const size_t bh = (size_t)(b * 16 + h);
                    if (which == 0) {
                        o_q[(bh * 2048 + l) * 64 + dd] = f2bf((y + bias0[d]) * 0.125f);
                    } else if (which == 1) {
                        o_k[(bh * 2048 + l) * 64 + dd] = f2bf(y + bias1[d]);
                    } else {
                        o_vt[(bh * 64 + dd) * 2048 + l] = f2bf(y + bias2[d]);
                    }
                } else {
                    o_f[(size_t)rr * 1024 + c] = y + bias0[c];
                }
            }
        }
    }
}

// ---------------- flash attention v4: permlane P-redistribute, 4-wave blocks ----------------
// grid: 1024 flat (32 q-tiles x 32 bh, XCD-swizzled). block: 256 (4 waves x 16 q-rows).

__global__ __launch_bounds__(256, 4) void attn_kernel(
    const u16* __restrict__ qb, const u16* __restrict__ kb,
    const u16* __restrict__ vtb, const float* __restrict__ bondf,
    u16* __restrict__ attnout)
{
    __shared__ u16 Ks[2][64 * 64];   // [buf][key][dk]   swizzled chunks
    __shared__ u16 Vs[2][64 * 64];   // [buf][dk][key]   swizzled chunks
    const int t = threadIdx.x;
    const int lane = t & 63, w = t >> 6;
    const int g = lane >> 4, r = lane & 15;
    const int sw = r & 7;
    const int pg = ((g & 1) << 1) | (g >> 1);   // key-chunk permutation from permlane16_swap
    const int flat = blockIdx.x;
    const int wg = (flat & 7) * 128 + (flat >> 3);
    const int bh = wg >> 5, qt = wg & 31;
    const int b = bh >> 4, h = bh & 15;
    const int q0 = qt * 64 + w * 16;
    const size_t kvBase = (size_t)bh * 2048 * 64;
    const size_t bondRow = ((size_t)b * 2048 + q0 + r) * 2048;

    // Q as B-operand fragments: lane gives Q[q0+r][kz*32+g*8+jj]
    bf16x8 aq[2];
#pragma unroll
    for (int kz = 0; kz < 2; ++kz)
        aq[kz] = *(const bf16x8*)&qb[kvBase + (size_t)(q0 + r) * 64 + kz * 32 + g * 8];

    const f32x4 zero4 = {0.f, 0.f, 0.f, 0.f};
    f32x4 o[4];
#pragma unroll
    for (int nf = 0; nf < 4; ++nf) o[nf] = zero4;
    float sm = 0.f;

    // prologue: stage K/V tile 0; bond tile 0 into registers
#pragma unroll
    for (int i = 0; i < 2; ++i) {
        const int idx = i * 256 + t;
        const int row = idx >> 3, ch = idx & 7;
        const int chg = ch ^ (row & 7);
        gld16(kb + kvBase + (size_t)row * 64 + chg * 8, (char*)&Ks[0][0] + idx * 16);
        gld16(vtb + ((size_t)bh * 64 + row) * 2048 + chg * 8, (char*)&Vs[0][0] + idx * 16);
    }
    float4 bd[4], bdn[4];
#pragma unroll
    for (int kf = 0; kf < 4; ++kf)
        bd[kf] = *(const float4*)&bondf[bondRow + kf * 16 + g * 4];
    __syncthreads();

    for (int it = 0; it < 32; ++it) {
        const int cur = it & 1;
        const int kt = it * 64;
        // issue K/V + bond prefetch for t+1 (stay in flight through compute)
        if (it < 31) {
            const int kt2 = kt + 64;
#pragma unroll
            for (int i = 0; i < 2; ++i) {
                const int idx = i * 256 + t;
                const int row = idx >> 3, ch = idx & 7;
                const int chg = ch ^ (row & 7);
                gld16(kb + kvBase + (size_t)(kt2 + row) * 64 + chg * 8, (char*)&Ks[cur ^ 1][0] + idx * 16);
                gld16(vtb + ((size_t)bh * 64 + row) * 2048 + kt2 + chg * 8, (char*)&Vs[cur ^ 1][0] + idx * 16);
            }
#pragma unroll
            for (int kf = 0; kf < 4; ++kf)
                bdn[kf] = *(const float4*)&bondf[bondRow + kt2 + kf * 16 + g * 4];
        }

        // S^T = mfma(K, Q): key = kf*16+g*4+j (rows), q = q0+r (cols)
        f32x4 st[4];
#pragma unroll
        for (int kf = 0; kf < 4; ++kf) st[kf] = zero4;
#pragma unroll
        for (int kz = 0; kz < 2; ++kz) {
            bf16x8 kfr[4];
#pragma unroll
            for (int kf = 0; kf < 4; ++kf)
                kfr[kf] = *(const bf16x8*)((const char*)&Ks[cur][0] +
                            (kf * 16 + r) * 128 + (((kz * 4 + g) ^ sw) * 16));
            __builtin_amdgcn_s_setprio(1);
#pragma unroll
            for (int kf = 0; kf < 4; ++kf)
                st[kf] = __builtin_amdgcn_mfma_f32_16x16x32_bf16(kfr[kf], aq[kz], st[kf], 0, 0, 0);
            __builtin_amdgcn_s_setprio(0);
        }

        // p = exp(s*bond), pack to bf16 pairs, lane-local row-sum
        uint32_t pkl[4], pkh[4];
#pragma unroll
        for (int kf = 0; kf < 4; ++kf) {
            const float p0 = __expf(st[kf][0] * bd[kf].x);
            const float p1 = __expf(st[kf][1] * bd[kf].y);
            const float p2 = __expf(st[kf][2] * bd[kf].z);
            const float p3 = __expf(st[kf][3] * bd[kf].w);
            sm += (p0 + p1) + (p2 + p3);
            pkl[kf] = packbf(p0, p1);
            pkh[kf] = packbf(p2, p3);
        }
        // cross-lane redistribute: after swaps, fragment kz holds physical keys
        // kz*32 + perm[g]*8 + jj, perm = [0,2,1,3] (pg)
        plswap16(pkl[0], pkl[1]);
        plswap16(pkh[0], pkh[1]);
        plswap16(pkl[2], pkl[3]);
        plswap16(pkh[2], pkh[3]);
        union { uint32_t u[4]; bf16x8 v; } ap0, ap1;
        ap0.u[0] = pkl[0]; ap0.u[1] = pkh[0]; ap0.u[2] = pkl[1]; ap0.u[3] = pkh[1];
        ap1.u[0] = pkl[2]; ap1.u[1] = pkh[2]; ap1.u[2] = pkl[3]; ap1.u[3] = pkh[3];

        // O += P * V : B-fragment read at key-chunk pg (matches permuted k-axis)
#pragma unroll
        for (int kz = 0; kz < 2; ++kz) {
            bf16x8 bv_[4];
#pragma unroll
            for (int nf = 0; nf < 4; ++nf)
                bv_[nf] = *(const bf16x8*)((const char*)&Vs[cur][0] +
                            (nf * 16 + r) * 128 + (((kz * 4 + pg) ^ sw) * 16));
            const bf16x8 ap = kz ? ap1.v : ap0.v;
            __builtin_amdgcn_s_setprio(1);
#pragma unroll
            for (int nf = 0; nf < 4; ++nf)
                o[nf] = __builtin_amdgcn_mfma_f32_16x16x32_bf16(ap, bv_[nf], o[nf], 0, 0, 0);
            __builtin_amdgcn_s_setprio(0);
        }

        // rotate bond regs (forces bond-load wait here, after compute)
        if (it < 31) {
#pragma unroll
            for (int kf = 0; kf < 4; ++kf) bd[kf] = bdn[kf];
        }
        __syncthreads();
    }

    // row sums: reduce across the 4 g-groups, then gather per accumulator row via shuffle
    sm += __shfl_xor(sm, 16, 64);
    sm += __shfl_xor(sm, 32, 64);
    float lv[4];
#pragma unroll
    for (int j = 0; j < 4; ++j)
        lv[j] = __shfl(sm, g * 4 + j, 16);   // source lane r' = g*4+j in own 16-group

#pragma unroll
    for (int j = 0; j < 4; ++j) {
        const float inv = 1.f / lv[j];
        const size_t orow = ((size_t)b * 2048 + q0 + g * 4 + j) * 1024 + h * 64;
#pragma unroll
        for (int nf = 0; nf < 4; ++nf)
            attnout[orow + nf * 16 + r] = f2bf(o[nf][j] * inv);
    }
}

// ---------------- launch ----------------

extern "C" void kernel_launch(void* const* d_in, const int* in_sizes, int n_in,
                              void* d_out, int out_size, void* d_ws, size_t ws_size,
                              hipStream_t stream) {
    (void)in_sizes; (void)n_in; (void)out_size; (void)ws_size;
    const float* x    = (const float*)d_in[0];
    const float* bond = (const float*)d_in[1];
    const float* Wq   = (const float*)d_in[2];
    const float* bq   = (const float*)d_in[3];
    const float* Wk   = (const float*)d_in[4];
    const float* bk   = (const float*)d_in[5];
    const float* Wv   = (const float*)d_in[6];
    const float* bv   = (const float*)d_in[7];
    const float* Wo   = (const float*)d_in[8];
    const float* bo   = (const float*)d_in[9];
    float* out = (float*)d_out;

    char* ws = (char*)d_ws;
    u16* xb      = (u16*)(ws);
    u16* wqkvt   = (u16*)(ws + 8388608);
    u16* wot     = (u16*)(ws + 14680064);
    u16* qb      = (u16*)(ws + 16777216);
    u16* kb_     = (u16*)(ws + 25165824);
    u16* vtb     = (u16*)(ws + 33554432);
    u16* attnout = (u16*)(ws + 58720256);

    dim3 tb(32, 8);
    transpose_bf16_kernel<<<dim3(32, 32), tb, 0, stream>>>(Wq, wqkvt);
    transpose_bf16_kernel<<<dim3(32, 32), tb, 0, stream>>>(Wk, wqkvt + 1024 * 1024);
    transpose_bf16_kernel<<<dim3(32, 32), tb, 0, stream>>>(Wv, wqkvt + 2 * 1024 * 1024);
    transpose_bf16_kernel<<<dim3(32, 32), tb, 0, stream>>>(Wo, wot);
    cvt_bf16_kernel<<<1024, 256, 0, stream>>>(x, xb, 4194304 / 4);

    gemm128<0><<<dim3(24, 32), 256, 0, stream>>>(xb, wqkvt, bq, bk, bv, qb, kb_, vtb, nullptr);
    attn_kernel<<<dim3(1024), 256, 0, stream>>>(qb, kb_, vtb, bond, attnout);
    gemm128<1><<<dim3(8, 32), 256, 0, stream>>>(attnout, wot, bo, nullptr, nullptr,
                                                nullptr, nullptr, nullptr, out);
}